// Round 1
// baseline (34.698 us; speedup 1.0000x reference)
//
#include <hip/hip_runtime.h>

// GALNLLLoss2d: fused 2x2 Cholesky-solve + log K1 Bessel NLL, mean-reduced.
// Inputs (f32): loc[B,2], m[B,2], L[B,2,2] (lower-tri, positive diag), x[B,2]
// Output: single f32 = -mean(log_prob)

#define C_LOG2   0.6931471805599453f
#define C_LOG2PI 1.8378770664093453f

__global__ __launch_bounds__(256) void gal_main_kernel(
    const float* __restrict__ loc, const float* __restrict__ m,
    const float* __restrict__ L,   const float* __restrict__ x,
    double* __restrict__ partial, int n)
{
    double acc = 0.0;
    const int stride = gridDim.x * blockDim.x;
    for (int i = blockIdx.x * blockDim.x + threadIdx.x; i < n; i += stride) {
        const float2 l2 = reinterpret_cast<const float2*>(loc)[i];
        const float2 m2 = reinterpret_cast<const float2*>(m)[i];
        const float2 x2 = reinterpret_cast<const float2*>(x)[i];
        const float4 L4 = reinterpret_cast<const float4*>(L)[i];
        // L = [[a, 0], [b, c]], a,c > 0 by construction
        const float a = L4.x, b = L4.z, c = L4.w;
        const float ia = 1.0f / a, ic = 1.0f / c;
        const float d0 = x2.x - l2.x, d1 = x2.y - l2.y;
        // y = L^{-1} v (forward substitution); v^T Sinv w = (L^{-1}v)·(L^{-1}w)
        const float ym0 = m2.x * ia;
        const float ym1 = (m2.y - b * ym0) * ic;
        const float yx0 = d0 * ia;
        const float yx1 = (d1 - b * yx0) * ic;
        const float qm  = ym0 * ym0 + ym1 * ym1;   // m^T Sinv m
        const float qx  = yx0 * yx0 + yx1 * yx1;   // diff^T Sinv diff
        const float qxm = yx0 * ym0 + yx1 * ym1;   // diff^T Sinv m
        const float s = 2.0f + qm;
        const float z = sqrtf(s * qx);

        // log(kve1(z)) - z, branchless with clamped safe args (A&S 9.8.3/7/8)
        const float zs = fminf(z, 2.0f);
        const float zl = fmaxf(z, 2.0f);
        // small: kve1 = (zK1(z)/z)*exp(z)  =>  log(kve1)-z = log(zK1(z)/z)
        float t = zs * 0.26666666666f;  // z/3.75
        t = t * t;
        const float i1 = zs * (0.5f + t * (0.87890594f + t * (0.51498869f
                       + t * (0.15084934f + t * (0.02658733f + t * (0.00301532f
                       + t * 0.00032411f))))));
        const float t2 = zs * zs * 0.25f;
        const float zk1 = zs * logf(zs * 0.5f) * i1 + 1.0f + t2 * (0.15443144f
                        + t2 * (-0.67278579f + t2 * (-0.18156897f
                        + t2 * (-0.01919402f + t2 * (-0.00110404f
                        + t2 * (-0.00004686f))))));
        const float lk_small = logf(zk1 / zs);
        // large: kve1 = poly(2/z)/sqrt(z)  =>  log(kve1)-z = log(poly)-0.5*log(z)-z
        const float u = 2.0f / zl;
        const float poly = 1.25331414f + u * (0.23498619f + u * (-0.03655620f
                         + u * (0.01504268f + u * (-0.00780353f + u * (0.00325614f
                         + u * (-0.00068245f))))));
        const float lk_large = logf(poly) - 0.5f * logf(zl) - z;
        const float lkz = (z <= 2.0f) ? lk_small : lk_large;

        const float log_prob = C_LOG2 + qxm - C_LOG2PI
                             - logf(fabsf(a * c))        // 0.5*logdet(Sinv)
                             + 0.5f * logf(qx / s)       // 0.5*nu*log(qx/(2+qm))
                             + lkz;
        acc += (double)log_prob;
    }
    // wave64 butterfly-free down-reduce, then cross-wave via LDS
    #pragma unroll
    for (int off = 32; off > 0; off >>= 1)
        acc += __shfl_down(acc, off);
    __shared__ double smem[4];
    const int lane = threadIdx.x & 63;
    const int wid  = threadIdx.x >> 6;
    if (lane == 0) smem[wid] = acc;
    __syncthreads();
    if (threadIdx.x == 0)
        partial[blockIdx.x] = smem[0] + smem[1] + smem[2] + smem[3];
}

__global__ __launch_bounds__(256) void gal_final_kernel(
    const double* __restrict__ partial, int nblocks,
    float* __restrict__ out, double inv_n)
{
    double acc = 0.0;
    for (int i = threadIdx.x; i < nblocks; i += 256)
        acc += partial[i];
    #pragma unroll
    for (int off = 32; off > 0; off >>= 1)
        acc += __shfl_down(acc, off);
    __shared__ double smem[4];
    const int lane = threadIdx.x & 63;
    const int wid  = threadIdx.x >> 6;
    if (lane == 0) smem[wid] = acc;
    __syncthreads();
    if (threadIdx.x == 0)
        out[0] = (float)(-(smem[0] + smem[1] + smem[2] + smem[3]) * inv_n);
}

extern "C" void kernel_launch(void* const* d_in, const int* in_sizes, int n_in,
                              void* d_out, int out_size, void* d_ws, size_t ws_size,
                              hipStream_t stream) {
    const float* loc = (const float*)d_in[0];
    const float* m   = (const float*)d_in[1];
    const float* L   = (const float*)d_in[2];
    const float* x   = (const float*)d_in[3];
    const int n = in_sizes[0] / 2;  // B rows

    int nblocks = 2048;  // 2048 * 256 threads, 8 rows/thread via grid-stride
    const size_t need = (size_t)nblocks * sizeof(double);
    if (ws_size < need) nblocks = (int)(ws_size / sizeof(double));
    double* partial = (double*)d_ws;

    gal_main_kernel<<<nblocks, 256, 0, stream>>>(loc, m, L, x, partial, n);
    gal_final_kernel<<<1, 256, 0, stream>>>(partial, nblocks, (float*)d_out,
                                            1.0 / (double)n);
}